// Round 9
// baseline (248.198 us; speedup 1.0000x reference)
//
#include <hip/hip_runtime.h>

#define G 4096
#define BSZ 2
#define NIN 8
#define HID 32
#define NLOG2E (-1.4426950408889634f)

typedef __attribute__((ext_vector_type(8))) short short8;
typedef __attribute__((ext_vector_type(4))) float floatx4;
typedef unsigned short ushort_t;
typedef unsigned int uint_t;

__device__ __forceinline__ float elu1(float v) {
    return v > 0.f ? v : (__expf(v) - 1.f);
}
__device__ __forceinline__ ushort_t f2bf(float f) {
    unsigned u = __float_as_uint(f);
    u += 0x7fffu + ((u >> 16) & 1u);
    return (ushort_t)(u >> 16);
}

// h = elu(x@W_infer+b); s_src/s_dst projections; hT bf16 [b][c][g] via LDS transpose.
__global__ __launch_bounds__(256) void k_setup1(
    const float* __restrict__ x, const float* __restrict__ W,
    const float* __restrict__ bias, const float* __restrict__ We,
    float* __restrict__ h0, ushort_t* __restrict__ hTb,
    float* __restrict__ ssrc, float* __restrict__ sdst) {
    __shared__ __align__(16) ushort_t hs[HID][264];
    int tid = threadIdx.x;
    int t = blockIdx.x * 256 + tid;
    int b = t >> 12;
    int g0 = (blockIdx.x & 15) * 256;
    float xin[NIN];
    const float* xp = x + t * NIN;
#pragma unroll
    for (int k = 0; k < NIN; k++) xin[k] = xp[k];
    float ss = 0.f, sd = 0.f;
    float* hp = h0 + (size_t)t * HID;
#pragma unroll
    for (int o = 0; o < HID; o++) {
        float v = bias[o];
#pragma unroll
        for (int k = 0; k < NIN; k++) v += xin[k] * W[k * HID + o];
        v = elu1(v);
        hp[o] = v;
        hs[o][tid] = f2bf(v);
        ss += v * We[o];
        sd += v * We[HID + o];
    }
    ssrc[t] = ss;
    sdst[t] = sd;
    __syncthreads();
#pragma unroll
    for (int p = 0; p < 4; p++) {
        int row = p * 8 + (tid >> 5);
        int c = (tid & 31) * 8;
        short8 v8 = *(const short8*)&hs[row][c];
        *(short8*)(void*)&hTb[(size_t)(b * HID + row) * G + g0 + c] = v8;
    }
}

// Fully fused MP block: 16 genes x 2 batches per block, full j-range.
// Staging: raw fp32 adjacency rows -> bit-pack in-register (nibble + shfl-OR)
// into LDS abits; ssrc pre-scaled into LDS. 8 waves = (jq 0..3) x (b 0..1);
// A-frag e computed in-register; 4-way LDS merge; node+merge MLP (+BN+proj+hT
// for layer 1) all in-block. No intermediate global traffic, no pack kernel.
template <bool DO_BN>
__global__ __launch_bounds__(512, 2) void k_fused(
    const float* __restrict__ adj, const float* __restrict__ ssrc,
    const float* __restrict__ sdst, const ushort_t* __restrict__ hTb_in,
    const float* __restrict__ bep, float coef, const float* __restrict__ hin,
    const float* __restrict__ Wn, const float* __restrict__ bnb,
    const float* __restrict__ Wm, const float* __restrict__ bmb,
    const float* __restrict__ gamma, const float* __restrict__ beta,
    const float* __restrict__ We2, float* __restrict__ outp,
    ushort_t* __restrict__ hTb_out, float* __restrict__ s2s,
    float* __restrict__ s2d) {
    union SMemU {
        float ssm[BSZ][G];                       // compute phase (32 KB)
        struct {                                 // post phase (~19.7 KB)
            float rec[32][68];
            float rec2[32][68];
            float esg[16][2];
            ushort_t tb[BSZ][HID][16];
        } p;
    };
    __shared__ __align__(16) SMemU sm;
    __shared__ __align__(16) uint_t abits[128][16];
    __shared__ __align__(16) float red[6][64][9];
    __shared__ __align__(16) float Wns[2048];
    __shared__ __align__(16) float Wms[2048];

    int tid = threadIdx.x;
    int g0 = blockIdx.x * 16;
    int l = tid & 63, w = tid >> 6;

    // stage weights (512 x 16B each)
    ((float4*)Wns)[tid] = ((const float4*)Wn)[tid];
    ((float4*)Wms)[tid] = ((const float4*)Wm)[tid];
    // stage ssrc (pre-scaled by -log2e): 8192 floats
#pragma unroll
    for (int r = 0; r < 4; r++) {
        int idx = r * 2048 + tid * 4;
        int bb = idx >> 12, j = idx & 4095;
        float4 s4 = *(const float4*)&ssrc[bb * G + j];
        s4.x *= NLOG2E; s4.y *= NLOG2E; s4.z *= NLOG2E; s4.w *= NLOG2E;
        *(float4*)&sm.ssm[bb][j] = s4;
    }
    // stage adjacency: wave w packs rows 2w, 2w+1 (fp32 -> bits).
    // Lane-consecutive float4 loads (1 KB/instr); nibble -> 32-bit word via
    // 3 shfl-or steps over 8-lane groups; one LDS store per word.
#pragma unroll
    for (int rr = 0; rr < 2; rr++) {
        int row = 2 * w + rr;
        const float* ar = adj + (size_t)(g0 + row) * G;
#pragma unroll
        for (int it = 0; it < 16; it++) {
            float4 v4 = *(const float4*)&ar[it * 256 + l * 4];
            uint_t nib = (uint_t)(v4.x != 0.f) | ((uint_t)(v4.y != 0.f) << 1) |
                         ((uint_t)(v4.z != 0.f) << 2) | ((uint_t)(v4.w != 0.f) << 3);
            uint_t wd = nib << ((l & 7) * 4);
            wd |= __shfl_xor(wd, 1);
            wd |= __shfl_xor(wd, 2);
            wd |= __shfl_xor(wd, 4);
            if ((l & 7) == 0) abits[it * 8 + (l >> 3)][row] = wd;
        }
    }

    int jq = w >> 1, b = w & 1;
    int m = l & 15, kg = l >> 4;
    float sd2 = (sdst[b * G + g0 + m] + bep[0]) * NLOG2E;
    float wm1 = 1.f - coef;
    int jstart = jq * 1024;
    const ushort_t* hb0 = hTb_in + (size_t)(b * HID + m) * G + jstart + kg * 8;
    const ushort_t* hb1 = hb0 + (size_t)16 * G;
    floatx4 c0 = {0.f, 0.f, 0.f, 0.f}, c1 = {0.f, 0.f, 0.f, 0.f};
    float es = 0.f;
    short8 pb0[2], pb1[2];
#pragma unroll
    for (int d = 0; d < 2; d++) {
        pb0[d] = *(const short8*)(const void*)(hb0 + d * 32);
        pb1[d] = *(const short8*)(const void*)(hb1 + d * 32);
    }
    __syncthreads();
    const float* svp = &sm.ssm[b][jstart + kg * 8];
    const uint_t* abp = &abits[jq * 32][m];

#pragma unroll 4
    for (int jc = 0; jc < 32; jc++) {
        int cur = jc & 1;
        short8 bf0 = pb0[cur], bf1 = pb1[cur];
        if (jc + 2 < 32) {
            int o = (jc + 2) * 32;
            pb0[cur] = *(const short8*)(const void*)(hb0 + o);
            pb1[cur] = *(const short8*)(const void*)(hb1 + o);
        }
        uint_t bw = abp[jc * 16];
        float4 s0 = *(const float4*)&svp[jc * 32];
        float4 s1 = *(const float4*)&svp[jc * 32 + 4];
        float sv[8] = {s0.x, s0.y, s0.z, s0.w, s1.x, s1.y, s1.z, s1.w};
        short8 af;
#pragma unroll
        for (int t = 0; t < 8; t++) {
            float bitf = (float)((bw >> (kg * 8 + t)) & 1u);
            float wgt = __builtin_fmaf(bitf, wm1, coef);   // exact for bit in {0,1}
            float ex = exp2f(sd2 + sv[t]);                 // = exp(-logit)
            float e = __builtin_amdgcn_rcpf(1.f + ex) * wgt;
            es += e;
            af[t] = (short)f2bf(e);
        }
        c0 = __builtin_amdgcn_mfma_f32_16x16x32_bf16(af, bf0, c0, 0, 0, 0);
        c1 = __builtin_amdgcn_mfma_f32_16x16x32_bf16(af, bf1, c1, 0, 0, 0);
    }
    // 4-way j-quarter merge
    if (jq) {
        int widx = (jq - 1) * 2 + b;
#pragma unroll
        for (int r = 0; r < 4; r++) {
            red[widx][l][r] = c0[r];
            red[widx][l][4 + r] = c1[r];
        }
        red[widx][l][8] = es;
    }
    __syncthreads();
    if (!jq) {
#pragma unroll
        for (int q = 0; q < 3; q++) {
            int widx = q * 2 + b;
#pragma unroll
            for (int r = 0; r < 4; r++) {
                c0[r] += red[widx][l][r];
                c1[r] += red[widx][l][4 + r];
            }
            es += red[widx][l][8];
        }
        es += __shfl_xor(es, 16);
        es += __shfl_xor(es, 32);
#pragma unroll
        for (int r = 0; r < 4; r++) {
            int gene = (l >> 4) * 4 + r;   // C/D: row=(l>>4)*4+reg, col=l&15
            sm.p.rec[gene * 2 + b][m] = c0[r];
            sm.p.rec[gene * 2 + b][16 + m] = c1[r];
        }
        if (l < 16) sm.p.esg[l][b] = es;
    }
    __syncthreads();

    // fill recv_dst half: rec[row][32+hh] = x_i * esum
    int rl = tid >> 5, hh = tid & 31;
#pragma unroll
    for (int rp = 0; rp < 2; rp++) {
        int row = rp * 16 + rl;
        int gene = row >> 1, bb = row & 1;
        float xv = hin[((size_t)(bb * G + g0 + gene)) * HID + hh];
        sm.p.rec[row][32 + hh] = xv * sm.p.esg[gene][bb];
    }
    __syncthreads();

    // post: node MLP + merge MLP (+BN etc.), 16 rows per pass
#pragma unroll
    for (int rp = 0; rp < 2; rp++) {
        int row = rp * 16 + rl;
        int gene = row >> 1, bb = row & 1;
        float v = bnb[hh];
#pragma unroll
        for (int k4 = 0; k4 < 16; k4++) {
            float4 r4 = *(const float4*)&sm.p.rec[row][k4 * 4];
            v += r4.x * Wns[(k4 * 4 + 0) * HID + hh];
            v += r4.y * Wns[(k4 * 4 + 1) * HID + hh];
            v += r4.z * Wns[(k4 * 4 + 2) * HID + hh];
            v += r4.w * Wns[(k4 * 4 + 3) * HID + hh];
        }
        v = elu1(v);
        float xv = hin[((size_t)(bb * G + g0 + gene)) * HID + hh];
        sm.p.rec2[row][hh] = v;
        sm.p.rec2[row][32 + hh] = xv;
        float u = bmb[hh];
#pragma unroll
        for (int k4 = 0; k4 < 16; k4++) {
            float4 r4 = *(const float4*)&sm.p.rec2[row][k4 * 4];
            u += r4.x * Wms[(k4 * 4 + 0) * HID + hh];
            u += r4.y * Wms[(k4 * 4 + 1) * HID + hh];
            u += r4.z * Wms[(k4 * 4 + 2) * HID + hh];
            u += r4.w * Wms[(k4 * 4 + 3) * HID + hh];
        }
        float h1v = elu1(u);
        if (!DO_BN) {
            outp[((size_t)(bb * G + g0 + gene)) * HID + hh] = h1v;
        } else {
            // wave holds gene's full 64 values (lanes 0-31: b=0, 32-63: b=1)
            float s = h1v, sq = h1v * h1v;
#pragma unroll
            for (int mm = 32; mm; mm >>= 1) {
                s += __shfl_xor(s, mm);
                sq += __shfl_xor(sq, mm);
            }
            float mu = s * (1.f / 64.f);
            float var = sq * (1.f / 64.f) - mu * mu;
            float rstd = rsqrtf(var + 1e-5f);
            float hn = (h1v - mu) * rstd * gamma[g0 + gene] + beta[g0 + gene];
            outp[((size_t)(bb * G + g0 + gene)) * HID + hh] = hn;
            sm.p.tb[bb][hh][gene] = f2bf(hn);
            float ps = hn * We2[hh], pd = hn * We2[HID + hh];
#pragma unroll
            for (int mm = 16; mm; mm >>= 1) {
                ps += __shfl_xor(ps, mm);
                pd += __shfl_xor(pd, mm);
            }
            if (hh == 0) {
                s2s[bb * G + g0 + gene] = ps;
                s2d[bb * G + g0 + gene] = pd;
            }
        }
    }
    if (DO_BN) {
        __syncthreads();
        if (tid < 128) {
            int b2 = tid >> 6, c = (tid >> 1) & 31, half = tid & 1;
            short8 v8 = *(const short8*)&sm.p.tb[b2][c][half * 8];
            *(short8*)(void*)&hTb_out[(size_t)(b2 * HID + c) * G + g0 + half * 8] = v8;
        }
    }
}

extern "C" void kernel_launch(void* const* d_in, const int* in_sizes, int n_in,
                              void* d_out, int out_size, void* d_ws, size_t ws_size,
                              hipStream_t stream) {
    const float* x      = (const float*)d_in[0];
    const float* edges1 = (const float*)d_in[1];
    const float* edges2 = (const float*)d_in[2];
    const float* W_inf  = (const float*)d_in[3];
    const float* b_inf  = (const float*)d_in[4];
    const float* W_e1   = (const float*)d_in[5];
    const float* b_e1   = (const float*)d_in[6];
    const float* W_e2   = (const float*)d_in[7];
    const float* b_e2   = (const float*)d_in[8];
    const float* W_n1   = (const float*)d_in[9];
    const float* b_n1   = (const float*)d_in[10];
    const float* W_n2   = (const float*)d_in[11];
    const float* b_n2   = (const float*)d_in[12];
    const float* W_m1   = (const float*)d_in[13];
    const float* b_m1   = (const float*)d_in[14];
    const float* W_m2   = (const float*)d_in[15];
    const float* b_m2   = (const float*)d_in[16];
    const float* bn_g   = (const float*)d_in[17];
    const float* bn_b   = (const float*)d_in[18];
    float* out = (float*)d_out;

    float* ws = (float*)d_ws;
    float* h0   = ws;                           // 262144 floats
    float* h1n  = ws + 262144;                  // 262144
    float* s1s  = ws + 524288;                  // 8192
    float* s1d  = ws + 532480;                  // 8192
    float* s2s  = ws + 540672;                  // 8192
    float* s2d  = ws + 548864;                  // 8192
    ushort_t* hTb  = (ushort_t*)(ws + 557056);  // 262144 ushorts = 131072 floats
    ushort_t* hTb2 = (ushort_t*)(ws + 688128);  // 262144 ushorts
    // total ~ 819200 floats = 3.3 MB

    const float ALPHA = 0.005f, BETA = 5e-5f;

    k_setup1<<<32, 256, 0, stream>>>(x, W_inf, b_inf, W_e1, h0, hTb, s1s, s1d);
    k_fused<true><<<G / 16, 512, 0, stream>>>(
        edges1, s1s, s1d, hTb, b_e1, ALPHA, h0, W_n1, b_n1, W_m1, b_m1,
        bn_g, bn_b, W_e2, h1n, hTb2, s2s, s2d);
    k_fused<false><<<G / 16, 512, 0, stream>>>(
        edges2, s2s, s2d, hTb2, b_e2, BETA, h1n, W_n2, b_n2, W_m2, b_m2,
        nullptr, nullptr, nullptr, out, nullptr, nullptr, nullptr);
}

// Round 10
// 239.767 us; speedup vs baseline: 1.0352x; 1.0352x over previous
//
#include <hip/hip_runtime.h>

#define G 4096
#define BSZ 2
#define NIN 8
#define HID 32
#define NLOG2E (-1.4426950408889634f)

typedef __attribute__((ext_vector_type(8))) short short8;
typedef __attribute__((ext_vector_type(4))) float floatx4;
typedef unsigned short ushort_t;
typedef unsigned int uint_t;

__device__ __forceinline__ float elu1(float v) {
    return v > 0.f ? v : (__expf(v) - 1.f);
}
__device__ __forceinline__ ushort_t f2bf(float f) {
    unsigned u = __float_as_uint(f);
    u += 0x7fffu + ((u >> 16) & 1u);
    return (ushort_t)(u >> 16);
}

// h = elu(x@W_infer+b); s_src/s_dst projections; hT bf16 [b][c][g] via LDS transpose.
__global__ __launch_bounds__(256) void k_setup1(
    const float* __restrict__ x, const float* __restrict__ W,
    const float* __restrict__ bias, const float* __restrict__ We,
    float* __restrict__ h0, ushort_t* __restrict__ hTb,
    float* __restrict__ ssrc, float* __restrict__ sdst) {
    __shared__ __align__(16) ushort_t hs[HID][264];
    int tid = threadIdx.x;
    int t = blockIdx.x * 256 + tid;
    int b = t >> 12;
    int g0 = (blockIdx.x & 15) * 256;
    float xin[NIN];
    const float* xp = x + t * NIN;
#pragma unroll
    for (int k = 0; k < NIN; k++) xin[k] = xp[k];
    float ss = 0.f, sd = 0.f;
    float* hp = h0 + (size_t)t * HID;
#pragma unroll
    for (int o = 0; o < HID; o++) {
        float v = bias[o];
#pragma unroll
        for (int k = 0; k < NIN; k++) v += xin[k] * W[k * HID + o];
        v = elu1(v);
        hp[o] = v;
        hs[o][tid] = f2bf(v);
        ss += v * We[o];
        sd += v * We[HID + o];
    }
    ssrc[t] = ss;
    sdst[t] = sd;
    __syncthreads();
#pragma unroll
    for (int p = 0; p < 4; p++) {
        int row = p * 8 + (tid >> 5);
        int c = (tid & 31) * 8;
        short8 v8 = *(const short8*)&hs[row][c];
        *(short8*)(void*)&hTb[(size_t)(b * HID + row) * G + g0 + c] = v8;
    }
}

// Fully fused MP block: 16 genes x 2 batches per block, full j-range.
// 1024 threads = 16 waves (b x jq0..7); block-cooperative SEQUENTIAL adjacency
// staging (step s = whole row g0+s, 16 KB contiguous by 1024 threads) with
// in-register bit-pack; compute: A-frag e in-register, 16 iters/wave; 8-way
// LDS merge; node+merge MLP (+BN+proj+hT for layer 1) in-block.
template <bool DO_BN>
__global__ __launch_bounds__(1024, 4) void k_fused(
    const float* __restrict__ adj, const float* __restrict__ ssrc,
    const float* __restrict__ sdst, const ushort_t* __restrict__ hTb_in,
    const float* __restrict__ bep, float coef, const float* __restrict__ hin,
    const float* __restrict__ Wn, const float* __restrict__ bnb,
    const float* __restrict__ Wm, const float* __restrict__ bmb,
    const float* __restrict__ gamma, const float* __restrict__ beta,
    const float* __restrict__ We2, float* __restrict__ outp,
    ushort_t* __restrict__ hTb_out, float* __restrict__ s2s,
    float* __restrict__ s2d) {
    union SMemU {
        float ssm[BSZ][G];                       // compute phase (32 KB)
        struct {                                 // post phase (~19.2 KB)
            float rec[32][68];
            float rec2[32][68];
            float esg[16][2];
            ushort_t tb[BSZ][HID][16];
        } p;
    };
    __shared__ __align__(16) SMemU sm;
    __shared__ __align__(16) uint_t abits[128][16];
    __shared__ __align__(16) float red[14][64][9];
    __shared__ __align__(16) float Wns[2048];
    __shared__ __align__(16) float Wms[2048];

    int tid = threadIdx.x;              // 0..1023
    int g0 = blockIdx.x * 16;
    int l = tid & 63, w = tid >> 6;     // wave 0..15
    int b = w >> 3, jq = w & 7;

    // stage weights: 512 float4 each
    if (tid < 512) {
        ((float4*)Wns)[tid] = ((const float4*)Wn)[tid];
    } else {
        int t2 = tid - 512;
        ((float4*)Wms)[t2] = ((const float4*)Wm)[t2];
    }
    // stage ssrc (pre-scaled by -log2e): 8192 floats, 2 float4/thread
#pragma unroll
    for (int r = 0; r < 2; r++) {
        int idx = r * 4096 + tid * 4;
        int bb = idx >> 12, j = idx & 4095;
        float4 s4 = *(const float4*)&ssrc[bb * G + j];
        s4.x *= NLOG2E; s4.y *= NLOG2E; s4.z *= NLOG2E; s4.w *= NLOG2E;
        *(float4*)&sm.ssm[bb][j] = s4;
    }
    // stage adjacency sequentially: step s = full row g0+s (16 KB by 1024 thr)
    {
        int jw = tid >> 3;                   // j-word 0..127
        bool st = (tid & 7) == 0;
        int sh = (tid & 7) * 4;
#pragma unroll
        for (int s = 0; s < 16; s++) {
            float4 v4 = *(const float4*)&adj[(size_t)(g0 + s) * G + tid * 4];
            uint_t nib = (uint_t)(v4.x != 0.f) | ((uint_t)(v4.y != 0.f) << 1) |
                         ((uint_t)(v4.z != 0.f) << 2) | ((uint_t)(v4.w != 0.f) << 3);
            uint_t wd = nib << sh;
            wd |= __shfl_xor(wd, 1);
            wd |= __shfl_xor(wd, 2);
            wd |= __shfl_xor(wd, 4);
            if (st) abits[jw][s] = wd;
        }
    }

    int m = l & 15, kg = l >> 4;
    float sd2 = (sdst[b * G + g0 + m] + bep[0]) * NLOG2E;
    float wm1 = 1.f - coef;
    int jstart = jq * 512;
    const ushort_t* hb0 = hTb_in + (size_t)(b * HID + m) * G + jstart + kg * 8;
    const ushort_t* hb1 = hb0 + (size_t)16 * G;
    floatx4 c0 = {0.f, 0.f, 0.f, 0.f}, c1 = {0.f, 0.f, 0.f, 0.f};
    float es = 0.f;
    short8 pb0[2], pb1[2];
#pragma unroll
    for (int d = 0; d < 2; d++) {
        pb0[d] = *(const short8*)(const void*)(hb0 + d * 32);
        pb1[d] = *(const short8*)(const void*)(hb1 + d * 32);
    }
    __syncthreads();
    const float* svp = &sm.ssm[b][jstart + kg * 8];
    const uint_t* abp = &abits[jq * 16][m];

#pragma unroll 4
    for (int jc = 0; jc < 16; jc++) {
        int cur = jc & 1;
        short8 bf0 = pb0[cur], bf1 = pb1[cur];
        if (jc + 2 < 16) {
            int o = (jc + 2) * 32;
            pb0[cur] = *(const short8*)(const void*)(hb0 + o);
            pb1[cur] = *(const short8*)(const void*)(hb1 + o);
        }
        uint_t bw = abp[jc * 16];
        float4 s0 = *(const float4*)&svp[jc * 32];
        float4 s1 = *(const float4*)&svp[jc * 32 + 4];
        float sv[8] = {s0.x, s0.y, s0.z, s0.w, s1.x, s1.y, s1.z, s1.w};
        short8 af;
#pragma unroll
        for (int t = 0; t < 8; t++) {
            float bitf = (float)((bw >> (kg * 8 + t)) & 1u);
            float wgt = __builtin_fmaf(bitf, wm1, coef);   // exact for bit in {0,1}
            float ex = exp2f(sd2 + sv[t]);                 // = exp(-logit)
            float e = __builtin_amdgcn_rcpf(1.f + ex) * wgt;
            es += e;
            af[t] = (short)f2bf(e);
        }
        c0 = __builtin_amdgcn_mfma_f32_16x16x32_bf16(af, bf0, c0, 0, 0, 0);
        c1 = __builtin_amdgcn_mfma_f32_16x16x32_bf16(af, bf1, c1, 0, 0, 0);
    }
    // 8-way jq merge
    if (jq) {
        int widx = b * 7 + jq - 1;
#pragma unroll
        for (int r = 0; r < 4; r++) {
            red[widx][l][r] = c0[r];
            red[widx][l][4 + r] = c1[r];
        }
        red[widx][l][8] = es;
    }
    __syncthreads();
    if (!jq) {
#pragma unroll
        for (int q = 0; q < 7; q++) {
            int widx = b * 7 + q;
#pragma unroll
            for (int r = 0; r < 4; r++) {
                c0[r] += red[widx][l][r];
                c1[r] += red[widx][l][4 + r];
            }
            es += red[widx][l][8];
        }
        es += __shfl_xor(es, 16);
        es += __shfl_xor(es, 32);
#pragma unroll
        for (int r = 0; r < 4; r++) {
            int gene = (l >> 4) * 4 + r;   // C/D: row=(l>>4)*4+reg, col=l&15
            sm.p.rec[gene * 2 + b][m] = c0[r];
            sm.p.rec[gene * 2 + b][16 + m] = c1[r];
        }
        if (l < 16) sm.p.esg[l][b] = es;
    }
    __syncthreads();

    // post: 32 rows x 32 cols = 1024 threads, single pass
    int rl = tid >> 5, hh = tid & 31;
    int gene = rl >> 1, bb = rl & 1;
    float xv = hin[((size_t)(bb * G + g0 + gene)) * HID + hh];
    sm.p.rec[rl][32 + hh] = xv * sm.p.esg[gene][bb];
    __syncthreads();

    float v = bnb[hh];
#pragma unroll
    for (int k4 = 0; k4 < 16; k4++) {
        float4 r4 = *(const float4*)&sm.p.rec[rl][k4 * 4];
        v += r4.x * Wns[(k4 * 4 + 0) * HID + hh];
        v += r4.y * Wns[(k4 * 4 + 1) * HID + hh];
        v += r4.z * Wns[(k4 * 4 + 2) * HID + hh];
        v += r4.w * Wns[(k4 * 4 + 3) * HID + hh];
    }
    v = elu1(v);
    sm.p.rec2[rl][hh] = v;
    sm.p.rec2[rl][32 + hh] = xv;
    // row handled by one half-wave: lockstep makes rec2 visible w/o barrier
    float u = bmb[hh];
#pragma unroll
    for (int k4 = 0; k4 < 16; k4++) {
        float4 r4 = *(const float4*)&sm.p.rec2[rl][k4 * 4];
        u += r4.x * Wms[(k4 * 4 + 0) * HID + hh];
        u += r4.y * Wms[(k4 * 4 + 1) * HID + hh];
        u += r4.z * Wms[(k4 * 4 + 2) * HID + hh];
        u += r4.w * Wms[(k4 * 4 + 3) * HID + hh];
    }
    float h1v = elu1(u);
    if (!DO_BN) {
        outp[((size_t)(bb * G + g0 + gene)) * HID + hh] = h1v;
    } else {
        // wave holds gene's full 64 values (lanes 0-31: b=0, 32-63: b=1)
        float s = h1v, sq = h1v * h1v;
#pragma unroll
        for (int mm = 32; mm; mm >>= 1) {
            s += __shfl_xor(s, mm);
            sq += __shfl_xor(sq, mm);
        }
        float mu = s * (1.f / 64.f);
        float var = sq * (1.f / 64.f) - mu * mu;
        float rstd = rsqrtf(var + 1e-5f);
        float hn = (h1v - mu) * rstd * gamma[g0 + gene] + beta[g0 + gene];
        outp[((size_t)(bb * G + g0 + gene)) * HID + hh] = hn;
        sm.p.tb[bb][hh][gene] = f2bf(hn);
        float ps = hn * We2[hh], pd = hn * We2[HID + hh];
#pragma unroll
        for (int mm = 16; mm; mm >>= 1) {
            ps += __shfl_xor(ps, mm);
            pd += __shfl_xor(pd, mm);
        }
        if (hh == 0) {
            s2s[bb * G + g0 + gene] = ps;
            s2d[bb * G + g0 + gene] = pd;
        }
        __syncthreads();
        if (tid < 128) {
            int b2 = tid >> 6, c = (tid >> 1) & 31, half = tid & 1;
            short8 v8 = *(const short8*)&sm.p.tb[b2][c][half * 8];
            *(short8*)(void*)&hTb_out[(size_t)(b2 * HID + c) * G + g0 + half * 8] = v8;
        }
    }
}

extern "C" void kernel_launch(void* const* d_in, const int* in_sizes, int n_in,
                              void* d_out, int out_size, void* d_ws, size_t ws_size,
                              hipStream_t stream) {
    const float* x      = (const float*)d_in[0];
    const float* edges1 = (const float*)d_in[1];
    const float* edges2 = (const float*)d_in[2];
    const float* W_inf  = (const float*)d_in[3];
    const float* b_inf  = (const float*)d_in[4];
    const float* W_e1   = (const float*)d_in[5];
    const float* b_e1   = (const float*)d_in[6];
    const float* W_e2   = (const float*)d_in[7];
    const float* b_e2   = (const float*)d_in[8];
    const float* W_n1   = (const float*)d_in[9];
    const float* b_n1   = (const float*)d_in[10];
    const float* W_n2   = (const float*)d_in[11];
    const float* b_n2   = (const float*)d_in[12];
    const float* W_m1   = (const float*)d_in[13];
    const float* b_m1   = (const float*)d_in[14];
    const float* W_m2   = (const float*)d_in[15];
    const float* b_m2   = (const float*)d_in[16];
    const float* bn_g   = (const float*)d_in[17];
    const float* bn_b   = (const float*)d_in[18];
    float* out = (float*)d_out;

    float* ws = (float*)d_ws;
    float* h0   = ws;                           // 262144 floats
    float* h1n  = ws + 262144;                  // 262144
    float* s1s  = ws + 524288;                  // 8192
    float* s1d  = ws + 532480;                  // 8192
    float* s2s  = ws + 540672;                  // 8192
    float* s2d  = ws + 548864;                  // 8192
    ushort_t* hTb  = (ushort_t*)(ws + 557056);  // 262144 ushorts = 131072 floats
    ushort_t* hTb2 = (ushort_t*)(ws + 688128);  // 262144 ushorts
    // total ~ 819200 floats = 3.3 MB

    const float ALPHA = 0.005f, BETA = 5e-5f;

    k_setup1<<<32, 256, 0, stream>>>(x, W_inf, b_inf, W_e1, h0, hTb, s1s, s1d);
    k_fused<true><<<G / 16, 1024, 0, stream>>>(
        edges1, s1s, s1d, hTb, b_e1, ALPHA, h0, W_n1, b_n1, W_m1, b_m1,
        bn_g, bn_b, W_e2, h1n, hTb2, s2s, s2d);
    k_fused<false><<<G / 16, 1024, 0, stream>>>(
        edges2, s2s, s2d, hTb2, b_e2, BETA, h1n, W_n2, b_n2, W_m2, b_m2,
        nullptr, nullptr, nullptr, out, nullptr, nullptr, nullptr);
}